// Round 4
// baseline (448.390 us; speedup 1.0000x reference)
//
#include <hip/hip_runtime.h>

#define NNODES 10000
#define NEDGES 4096
#define INF 300
#define OUTF 150
#define EPB 16                      // edges per block
#define NGROUPS (NEDGES / EPB)      // 256
#define SPLITK 6                    // over combined K = 600 ([ef*h|h] @ [W;B])
#define KCHUNK 100                  // 600/6; chunks 0..2 -> W (ef-scaled h), 3..5 -> B (raw h)
#define ETHREADS 192                // lanes 0..149 compute, 150..165 do counts

#define SUMS_N (NNODES * OUTF)

// No launch_bounds: default VGPR budget (<=128) is plenty and leaves the
// compiler room to pipeline the W column loads across K iterations.
__global__ void edge_msg_kernel(
    const float* __restrict__ feat, const float* __restrict__ efeat,
    const float* __restrict__ W, const float* __restrict__ B,
    const int* __restrict__ src, const int* __restrict__ dst,
    float* __restrict__ sums, float* __restrict__ cnts)
{
    __shared__ float hA[EPB][KCHUNK];   // staged A-chunk (6.4 KB)
    __shared__ float s_ef[EPB];
    __shared__ int   s_dst[EPB];
    __shared__ int   s_src[EPB];

    const int tid = threadIdx.x;
    const int kc  = blockIdx.x / NGROUPS;     // consecutive blocks share kc -> same W chunk in L2
    const int grp = blockIdx.x - kc * NGROUPS;
    const int e0  = grp * EPB;

    const bool  isW = (kc < 3);               // wave-uniform
    const float* M  = isW ? W : B;
    const int   k0  = isW ? kc * KCHUNK : kc * KCHUNK - INF;   // row offset within M

    if (tid < EPB) {
        const int e = e0 + tid;
        s_src[tid] = src[e];
        s_dst[tid] = dst[e];
        s_ef[tid]  = efeat[e];
    }
    __syncthreads();

    // Stage K-chunk of the 16 gathered rows (25 float4 per row).
    for (int q = tid; q < EPB * (KCHUNK / 4); q += ETHREADS) {
        const int el = q / (KCHUNK / 4);
        const int j4 = q - el * (KCHUNK / 4);
        float4 v = *(const float4*)(feat + (size_t)s_src[el] * INF + k0 + 4 * j4);
        if (isW) {
            const float ef = s_ef[el];
            v.x *= ef; v.y *= ef; v.z *= ef; v.w *= ef;
        }
        *(float4*)&hA[el][4 * j4] = v;
    }
    __syncthreads();

    if (tid < OUTF) {
        float acc[EPB];
        #pragma unroll
        for (int e = 0; e < EPB; ++e) acc[e] = 0.f;

        const float* Wc = M + (size_t)k0 * OUTF + tid;   // column o = tid, row stride OUTF

        // Manual 2-deep pipeline on the W column loads (4 rows at a time).
        float4 wv;
        wv.x = Wc[0]; wv.y = Wc[OUTF]; wv.z = Wc[2 * OUTF]; wv.w = Wc[3 * OUTF];
        #pragma unroll 5
        for (int i4 = 0; i4 < KCHUNK; i4 += 4) {
            float4 wn = wv;
            if (i4 + 4 < KCHUNK) {
                const float* Wn = Wc + (size_t)(i4 + 4) * OUTF;
                wn.x = Wn[0]; wn.y = Wn[OUTF]; wn.z = Wn[2 * OUTF]; wn.w = Wn[3 * OUTF];
            }
            #pragma unroll
            for (int e = 0; e < EPB; ++e) {
                const float4 h = *(const float4*)&hA[e][i4];   // same-addr broadcast, conflict-free
                acc[e] = fmaf(h.w, wv.w, fmaf(h.z, wv.z,
                         fmaf(h.y, wv.y, fmaf(h.x, wv.x, acc[e]))));
            }
            wv = wn;
        }
        #pragma unroll
        for (int e = 0; e < EPB; ++e)
            atomicAdd(&sums[(size_t)s_dst[e] * OUTF + tid], acc[e]);
    } else if (kc == 0 && tid < OUTF + EPB) {
        atomicAdd(&cnts[s_dst[tid - OUTF]], 1.0f);   // count each edge once
    }
}

__global__ __launch_bounds__(256) void finalize_kernel(
    const float* __restrict__ sums, const float* __restrict__ cnts,
    const float* __restrict__ bias, float* __restrict__ out)
{
    const int idx = blockIdx.x * blockDim.x + threadIdx.x;
    if (idx < SUMS_N) {
        const int n = idx / OUTF;
        const int o = idx - n * OUTF;
        const float c = cnts[n];
        const float m = sums[idx] / fmaxf(c, 1.0f);
        const float v = m + bias[o];
        out[idx] = v > 0.f ? v : 0.f;
    }
}

extern "C" void kernel_launch(void* const* d_in, const int* in_sizes, int n_in,
                              void* d_out, int out_size, void* d_ws, size_t ws_size,
                              hipStream_t stream) {
    const float* feat  = (const float*)d_in[0];
    const float* efeat = (const float*)d_in[1];
    const float* W     = (const float*)d_in[2];
    const float* B     = (const float*)d_in[3];
    const float* bias  = (const float*)d_in[4];
    const int*   src   = (const int*)d_in[5];
    const int*   dst   = (const int*)d_in[6];
    float* out  = (float*)d_out;

    float* sums = (float*)d_ws;                 // [NNODES*OUTF]
    float* cnts = sums + SUMS_N;                // [NNODES]

    hipMemsetAsync(d_ws, 0, (size_t)(SUMS_N + NNODES) * sizeof(float), stream);

    edge_msg_kernel<<<NGROUPS * SPLITK, ETHREADS, 0, stream>>>(
        feat, efeat, W, B, src, dst, sums, cnts);

    finalize_kernel<<<(SUMS_N + 255) / 256, 256, 0, stream>>>(sums, cnts, bias, out);
}

// Round 5
// 104.804 us; speedup vs baseline: 4.2784x; 4.2784x over previous
//
#include <hip/hip_runtime.h>

#define NNODES 10000
#define NEDGES 4096
#define INF 300
#define OUTF 150
#define EPB 16                      // edges per block
#define NGROUPS (NEDGES / EPB)      // 256
#define SPLITK 5                    // K split over INF; 300/5 = 60
#define KCHUNK (INF / SPLITK)       // 60 (mult of 4 -> float4 staging stays 16B-aligned)
#define ETHREADS 192                // lanes 0..149 compute, 150..165 do counts

#define SUMS_N (NNODES * OUTF)

// launch_bounds(192,4): cap VGPR at 128 (we need ~60) -> no scratch spill
// (R4's 1.3 GB spill traffic), while allowing >=4 waves/EU occupancy.
__global__ __launch_bounds__(ETHREADS, 4) void edge_msg_kernel(
    const float* __restrict__ feat, const float* __restrict__ efeat,
    const float* __restrict__ W, const float* __restrict__ B,
    const int* __restrict__ src, const int* __restrict__ dst,
    float* __restrict__ sums, float* __restrict__ cnts)
{
    __shared__ float hA[EPB][KCHUNK];   // raw gathered h chunk (3.84 KB)
    __shared__ float s_ef[EPB];
    __shared__ int   s_dst[EPB];
    __shared__ int   s_src[EPB];

    const int tid = threadIdx.x;
    const int kc  = blockIdx.x / NGROUPS;   // consecutive blocks share kc -> same W rows in L2
    const int grp = blockIdx.x - kc * NGROUPS;
    const int e0  = grp * EPB;
    const int k0  = kc * KCHUNK;

    if (tid < EPB) {
        const int e = e0 + tid;
        s_src[tid] = src[e];
        s_dst[tid] = dst[e];
        s_ef[tid]  = efeat[e];
    }
    __syncthreads();

    // Stage raw h K-chunk for 16 edges: 16 rows x 15 float4 (16B-aligned).
    for (int q = tid; q < EPB * (KCHUNK / 4); q += ETHREADS) {
        const int el = q / (KCHUNK / 4);
        const int j4 = q - el * (KCHUNK / 4);
        *(float4*)&hA[el][4 * j4] =
            *(const float4*)(feat + (size_t)s_src[el] * INF + k0 + 4 * j4);
    }
    __syncthreads();

    if (tid < OUTF) {
        // dual accumulators: h read ONCE feeds both h@W and h@B (2 FMA / h-elem)
        float accW[EPB], accB[EPB];
        #pragma unroll
        for (int e = 0; e < EPB; ++e) { accW[e] = 0.f; accB[e] = 0.f; }

        const float* Wc = W + (size_t)k0 * OUTF + tid;  // column o = tid
        const float* Bc = B + (size_t)k0 * OUTF + tid;

        #pragma unroll 3
        for (int i4 = 0; i4 < KCHUNK; i4 += 4) {
            const float w0 = Wc[(size_t)(i4 + 0) * OUTF];
            const float w1 = Wc[(size_t)(i4 + 1) * OUTF];
            const float w2 = Wc[(size_t)(i4 + 2) * OUTF];
            const float w3 = Wc[(size_t)(i4 + 3) * OUTF];
            const float b0 = Bc[(size_t)(i4 + 0) * OUTF];
            const float b1 = Bc[(size_t)(i4 + 1) * OUTF];
            const float b2 = Bc[(size_t)(i4 + 2) * OUTF];
            const float b3 = Bc[(size_t)(i4 + 3) * OUTF];
            #pragma unroll
            for (int e = 0; e < EPB; ++e) {
                const float4 h = *(const float4*)&hA[e][i4];  // broadcast, conflict-free
                accW[e] = fmaf(h.w, w3, fmaf(h.z, w2, fmaf(h.y, w1, fmaf(h.x, w0, accW[e]))));
                accB[e] = fmaf(h.w, b3, fmaf(h.z, b2, fmaf(h.y, b1, fmaf(h.x, b0, accB[e]))));
            }
        }
        // partial msg for this K-chunk (linear in K-chunk -> split-K atomics OK)
        #pragma unroll
        for (int e = 0; e < EPB; ++e) {
            const float msg = fmaf(s_ef[e], accW[e], accB[e]);
            atomicAdd(&sums[(size_t)s_dst[e] * OUTF + tid], msg);
        }
    } else if (kc == 0 && tid < OUTF + EPB) {
        atomicAdd(&cnts[s_dst[tid - OUTF]], 1.0f);   // each edge counted once
    }
}

__global__ __launch_bounds__(256) void finalize_kernel(
    const float* __restrict__ sums, const float* __restrict__ cnts,
    const float* __restrict__ bias, float* __restrict__ out)
{
    const int idx = blockIdx.x * blockDim.x + threadIdx.x;
    if (idx < SUMS_N) {
        const int n = idx / OUTF;
        const int o = idx - n * OUTF;
        const float c = cnts[n];
        const float m = sums[idx] / fmaxf(c, 1.0f);
        const float v = m + bias[o];
        out[idx] = v > 0.f ? v : 0.f;
    }
}

extern "C" void kernel_launch(void* const* d_in, const int* in_sizes, int n_in,
                              void* d_out, int out_size, void* d_ws, size_t ws_size,
                              hipStream_t stream) {
    const float* feat  = (const float*)d_in[0];
    const float* efeat = (const float*)d_in[1];
    const float* W     = (const float*)d_in[2];
    const float* B     = (const float*)d_in[3];
    const float* bias  = (const float*)d_in[4];
    const int*   src   = (const int*)d_in[5];
    const int*   dst   = (const int*)d_in[6];
    float* out  = (float*)d_out;

    float* sums = (float*)d_ws;                 // [NNODES*OUTF]
    float* cnts = sums + SUMS_N;                // [NNODES]

    hipMemsetAsync(d_ws, 0, (size_t)(SUMS_N + NNODES) * sizeof(float), stream);

    edge_msg_kernel<<<NGROUPS * SPLITK, ETHREADS, 0, stream>>>(
        feat, efeat, W, B, src, dst, sums, cnts);

    finalize_kernel<<<(SUMS_N + 255) / 256, 256, 0, stream>>>(sums, cnts, bias, out);
}

// Round 6
// 101.440 us; speedup vs baseline: 4.4202x; 1.0332x over previous
//
#include <hip/hip_runtime.h>

#define NNODES 10000
#define NEDGES 4096
#define INF 300
#define OUTF 150
#define EPB 16                      // edges per block
#define NGROUPS (NEDGES / EPB)      // 256
#define SPLITK 5                    // K split over INF; 300/5 = 60
#define KCHUNK (INF / SPLITK)       // 60
#define PHASES 3                    // 3 register-burst phases of 20 rows each
#define PROWS (KCHUNK / PHASES)     // 20 rows per phase -> 40 burst regs
#define ETHREADS 192                // lanes 0..149 compute, 150..165 do counts

#define SUMS_N (NNODES * OUTF)

// launch_bounds(192,4): 128-VGPR cap. Live set ~96 regs (40 burst + 32 acc +
// addressing) -> no scratch spill (R4 lesson), >=4 waves/EU occupancy.
__global__ __launch_bounds__(ETHREADS, 4) void edge_msg_kernel(
    const float* __restrict__ feat, const float* __restrict__ efeat,
    const float* __restrict__ W, const float* __restrict__ B,
    const int* __restrict__ src, const int* __restrict__ dst,
    float* __restrict__ sums, float* __restrict__ cnts)
{
    __shared__ float hA[EPB][KCHUNK];   // gathered h chunk (3.84 KB)
    __shared__ float s_ef[EPB];
    __shared__ int   s_dst[EPB];
    __shared__ int   s_src[EPB];

    const int tid = threadIdx.x;
    const int kc  = blockIdx.x / NGROUPS;   // consecutive blocks share kc
    const int grp = blockIdx.x - kc * NGROUPS;
    const int e0  = grp * EPB;
    const int k0  = kc * KCHUNK;

    if (tid < EPB) {
        const int e = e0 + tid;
        s_src[tid] = src[e];
        s_dst[tid] = dst[e];
        s_ef[tid]  = efeat[e];
    }
    __syncthreads();

    // Stage h K-chunk for 16 edges: 16 rows x 15 float4 (16B-aligned).
    for (int q = tid; q < EPB * (KCHUNK / 4); q += ETHREADS) {
        const int el = q / (KCHUNK / 4);
        const int j4 = q - el * (KCHUNK / 4);
        *(float4*)&hA[el][4 * j4] =
            *(const float4*)(feat + (size_t)s_src[el] * INF + k0 + 4 * j4);
    }
    __syncthreads();

    if (tid < OUTF) {
        float accW[EPB], accB[EPB];     // dual acc: each h elem feeds 2 FMAs
        #pragma unroll
        for (int e = 0; e < EPB; ++e) { accW[e] = 0.f; accB[e] = 0.f; }

        const float* Wc = W + (size_t)k0 * OUTF + tid;  // column o = tid
        const float* Bc = B + (size_t)k0 * OUTF + tid;

        // 3 phases; all indices compile-time after unroll -> burst loads are
        // 40 independent L2 requests issued back-to-back (one latency wait),
        // and phase p+1's burst can hoist above phase p's FMA tail.
        #pragma unroll
        for (int ph = 0; ph < PHASES; ++ph) {
            const int base = ph * PROWS;
            float wr[PROWS], br[PROWS];
            #pragma unroll
            for (int r = 0; r < PROWS; ++r) {
                wr[r] = Wc[(size_t)(base + r) * OUTF];
                br[r] = Bc[(size_t)(base + r) * OUTF];
            }
            #pragma unroll
            for (int i4 = 0; i4 < PROWS; i4 += 4) {
                #pragma unroll
                for (int e = 0; e < EPB; ++e) {
                    const float4 h = *(const float4*)&hA[e][base + i4]; // broadcast, conflict-free
                    accW[e] = fmaf(h.w, wr[i4 + 3], fmaf(h.z, wr[i4 + 2],
                              fmaf(h.y, wr[i4 + 1], fmaf(h.x, wr[i4 + 0], accW[e]))));
                    accB[e] = fmaf(h.w, br[i4 + 3], fmaf(h.z, br[i4 + 2],
                              fmaf(h.y, br[i4 + 1], fmaf(h.x, br[i4 + 0], accB[e]))));
                }
            }
        }
        // partial msg for this K-chunk (linear in K -> split-K atomics OK)
        #pragma unroll
        for (int e = 0; e < EPB; ++e) {
            const float msg = fmaf(s_ef[e], accW[e], accB[e]);
            atomicAdd(&sums[(size_t)s_dst[e] * OUTF + tid], msg);
        }
    } else if (kc == 0 && tid < OUTF + EPB) {
        atomicAdd(&cnts[s_dst[tid - OUTF]], 1.0f);   // each edge counted once
    }
}

__global__ __launch_bounds__(256) void finalize_kernel(
    const float* __restrict__ sums, const float* __restrict__ cnts,
    const float* __restrict__ bias, float* __restrict__ out)
{
    const int idx = blockIdx.x * blockDim.x + threadIdx.x;
    if (idx < SUMS_N) {
        const int n = idx / OUTF;
        const int o = idx - n * OUTF;
        const float c = cnts[n];
        const float m = sums[idx] / fmaxf(c, 1.0f);
        const float v = m + bias[o];
        out[idx] = v > 0.f ? v : 0.f;
    }
}

extern "C" void kernel_launch(void* const* d_in, const int* in_sizes, int n_in,
                              void* d_out, int out_size, void* d_ws, size_t ws_size,
                              hipStream_t stream) {
    const float* feat  = (const float*)d_in[0];
    const float* efeat = (const float*)d_in[1];
    const float* W     = (const float*)d_in[2];
    const float* B     = (const float*)d_in[3];
    const float* bias  = (const float*)d_in[4];
    const int*   src   = (const int*)d_in[5];
    const int*   dst   = (const int*)d_in[6];
    float* out  = (float*)d_out;

    float* sums = (float*)d_ws;                 // [NNODES*OUTF]
    float* cnts = sums + SUMS_N;                // [NNODES]

    hipMemsetAsync(d_ws, 0, (size_t)(SUMS_N + NNODES) * sizeof(float), stream);

    edge_msg_kernel<<<NGROUPS * SPLITK, ETHREADS, 0, stream>>>(
        feat, efeat, W, B, src, dst, sums, cnts);

    finalize_kernel<<<(SUMS_N + 255) / 256, 256, 0, stream>>>(sums, cnts, bias, out);
}